// Round 10
// baseline (463.947 us; speedup 1.0000x reference)
//
#include <hip/hip_runtime.h>
#include <hip/hip_bf16.h>
#include <hip/hip_cooperative_groups.h>

namespace cg = cooperative_groups;

#define NN 50000
#define EE 800000
#define DD 128
#define F1 256   // H*HID after conv1
#define F2 128   // OUT
#define NB196 196

using short8  = __attribute__((ext_vector_type(8))) short;
using floatx4 = __attribute__((ext_vector_type(4))) float;

__device__ inline float bf2f(ushort u) { return __uint_as_float(((unsigned)u) << 16); }
__device__ inline ushort f2bf(float f) {
    unsigned u = __float_as_uint(f);
    u += 0x7fffu + ((u >> 16) & 1u);      // round-to-nearest-even
    return (ushort)(u >> 16);
}

// ---------------- cooperative CSR build + weight converts (one kernel) ----------------
__global__ __launch_bounds__(256) void k_build(
    const int* __restrict__ esrc, const int* __restrict__ edst,
    int* __restrict__ cnt,        // reused as cursor in phase 4
    int* __restrict__ offsets, int* __restrict__ sums, int* __restrict__ srcs,
    const float* __restrict__ W1, ushort* __restrict__ W1t,
    const float* __restrict__ W2, ushort* __restrict__ W2t,
    const float* __restrict__ Wo, ushort* __restrict__ Wot,
    const float* __restrict__ b2, const float* __restrict__ bo,
    float* __restrict__ bc) {
    cg::grid_group grid = cg::this_grid();
    const int tid = blockIdx.x * 256 + threadIdx.x;
    const int NT  = gridDim.x * 256;
    __shared__ int s[256];

    // phase 0: zero counters
    for (int i = tid; i < NN; i += NT) cnt[i] = 0;
    grid.sync();

    // phase 1: edge histogram + weight transposes + bc
    for (int i = tid; i < EE; i += NT) atomicAdd(&cnt[edst[i]], 1);
    for (int i = tid; i < DD * F1; i += NT) {
        int k = i / F1, n = i % F1;
        W1t[(size_t)n * DD + k] = f2bf(W1[(size_t)k * F1 + n]);
    }
    for (int i = tid; i < F1 * F2; i += NT) {
        int k = i / F2, n = i % F2;
        W2t[(size_t)n * F1 + k] = f2bf(W2[(size_t)k * F2 + n]);
    }
    for (int i = tid; i < F2 * F2; i += NT) {
        int k = i / F2, n = i % F2;
        Wot[(size_t)n * F2 + k] = f2bf(Wo[(size_t)k * F2 + n]);
    }
    if (tid < F2) {
        float acc = bo[tid];
        for (int k = 0; k < F2; ++k) acc += b2[k] * Wo[(size_t)k * F2 + tid];
        bc[tid] = acc;
    }
    grid.sync();

    // phase 2: block-local exclusive scan of (cnt+1), blocks 0..195
    if (blockIdx.x < NB196) {
        int i = blockIdx.x * 256 + threadIdx.x;
        int v = (i < NN) ? cnt[i] + 1 : 0;   // +1 self-loop
        s[threadIdx.x] = v;
        __syncthreads();
        for (int off = 1; off < 256; off <<= 1) {
            int t2 = (threadIdx.x >= off) ? s[threadIdx.x - off] : 0;
            __syncthreads();
            s[threadIdx.x] += t2;
            __syncthreads();
        }
        if (i < NN) offsets[i] = s[threadIdx.x] - v;
        if (threadIdx.x == 255) sums[blockIdx.x] = s[255];
    }
    grid.sync();

    // phase 3: every block redundantly scans block sums; apply base; fill cursor
    {
        int v = (threadIdx.x < NB196) ? sums[threadIdx.x] : 0;
        s[threadIdx.x] = v;
        __syncthreads();
        for (int off = 1; off < 256; off <<= 1) {
            int t2 = (threadIdx.x >= off) ? s[threadIdx.x - off] : 0;
            __syncthreads();
            s[threadIdx.x] += t2;
            __syncthreads();
        }
        if (blockIdx.x < NB196) {
            int base = (blockIdx.x == 0) ? 0 : s[blockIdx.x - 1];
            int i = blockIdx.x * 256 + threadIdx.x;
            if (i < NN) {
                int o = offsets[i] + base;
                offsets[i] = o;
                cnt[i] = o;                  // cursor
            }
        }
        if (blockIdx.x == 0 && threadIdx.x == 0) offsets[NN] = EE + NN;
    }
    grid.sync();

    // phase 4: scatter edges (atomic cursor) + self-loop at last slot (no atomic)
    for (int i = tid; i < EE; i += NT) {
        int pos = atomicAdd(&cnt[edst[i]], 1);
        srcs[pos] = esrc[i];
    }
    for (int i = tid; i < NN; i += NT) srcs[offsets[i + 1] - 1] = i;
}

// ---------------- conv1 GEMM (128x128 tile) + fused emb-gather + 8-head logits ----------------
__global__ __launch_bounds__(256, 2) void k_gemm1(
    const int* __restrict__ x, const float* __restrict__ emb,
    const ushort* __restrict__ Bt,
    ushort* __restrict__ Cout,
    const float* __restrict__ avs, const float* __restrict__ avd,
    float* __restrict__ out_s, float* __restrict__ out_d) {
    __shared__ ushort As[128][72];   // [m][k]
    __shared__ ushort Bs[128][72];   // [n][k]
    const int t    = threadIdx.x;
    const int lane = t & 63;
    const int w    = t >> 6;
    const int wr   = w >> 1, wc = w & 1;
    const int m0   = blockIdx.x * 128;
    const int n0   = blockIdx.y * 128;
    floatx4 acc[4][4] = {};
    for (int k0 = 0; k0 < DD; k0 += 64) {
        #pragma unroll
        for (int p = 0; p < 4; ++p) {
            int linear = p * 2048 + t * 8;
            int row = linear >> 6;
            int col = linear & 63;
            short8 va = {};
            int gm = m0 + row;
            if (gm < NN) {
                const float* er = emb + (size_t)x[gm] * DD + k0 + col;
                float4 f0 = *(const float4*)er;
                float4 f1 = *(const float4*)(er + 4);
                va[0] = f2bf(f0.x); va[1] = f2bf(f0.y);
                va[2] = f2bf(f0.z); va[3] = f2bf(f0.w);
                va[4] = f2bf(f1.x); va[5] = f2bf(f1.y);
                va[6] = f2bf(f1.z); va[7] = f2bf(f1.w);
            }
            *(short8*)&As[row][col] = va;
            short8 vb = *(const short8*)(Bt + (size_t)(n0 + row) * DD + k0 + col);
            *(short8*)&Bs[row][col] = vb;
        }
        __syncthreads();
        #pragma unroll
        for (int kk = 0; kk < 64; kk += 32) {
            const int q8 = (lane >> 4) * 8;
            short8 af[4], bf[4];
            #pragma unroll
            for (int i = 0; i < 4; ++i)
                af[i] = *(const short8*)&As[wr * 64 + i * 16 + (lane & 15)][kk + q8];
            #pragma unroll
            for (int j = 0; j < 4; ++j)
                bf[j] = *(const short8*)&Bs[wc * 64 + j * 16 + (lane & 15)][kk + q8];
            #pragma unroll
            for (int i = 0; i < 4; ++i)
                #pragma unroll
                for (int j = 0; j < 4; ++j)
                    acc[i][j] = __builtin_amdgcn_mfma_f32_16x16x32_bf16(
                        af[i], bf[j], acc[i][j], 0, 0, 0);
        }
        __syncthreads();
    }
    const int r0 = (lane >> 4) * 4;
    const int cc = lane & 15;
    float as0 = avs[n0 + wc * 64 +  0 + cc], ad0 = avd[n0 + wc * 64 +  0 + cc];
    float as1 = avs[n0 + wc * 64 + 16 + cc], ad1 = avd[n0 + wc * 64 + 16 + cc];
    float as2 = avs[n0 + wc * 64 + 32 + cc], ad2 = avd[n0 + wc * 64 + 32 + cc];
    float as3 = avs[n0 + wc * 64 + 48 + cc], ad3 = avd[n0 + wc * 64 + 48 + cc];
    #pragma unroll
    for (int i = 0; i < 4; ++i) {
        #pragma unroll
        for (int r = 0; r < 4; ++r) {
            int m = m0 + wr * 64 + i * 16 + r0 + r;
            float hs0 = acc[i][0][r] * as0 + acc[i][1][r] * as1;
            float hs1 = acc[i][2][r] * as2 + acc[i][3][r] * as3;
            float hd0 = acc[i][0][r] * ad0 + acc[i][1][r] * ad1;
            float hd1 = acc[i][2][r] * ad2 + acc[i][3][r] * ad3;
            #pragma unroll
            for (int mask = 1; mask < 16; mask <<= 1) {
                hs0 += __shfl_xor(hs0, mask);
                hs1 += __shfl_xor(hs1, mask);
                hd0 += __shfl_xor(hd0, mask);
                hd1 += __shfl_xor(hd1, mask);
            }
            if (cc == 0 && m < NN) {
                int gh = (n0 >> 5) + wc * 2;
                out_s[m * 8 + gh] = hs0;   out_s[m * 8 + gh + 1] = hs1;
                out_d[m * 8 + gh] = hd0;   out_d[m * 8 + gh + 1] = hd1;
            }
            if (m < NN) {
                #pragma unroll
                for (int j = 0; j < 4; ++j)
                    Cout[(size_t)m * F1 + n0 + wc * 64 + j * 16 + cc] = f2bf(acc[i][j][r]);
            }
        }
    }
}

// ---------------- fused conv2 GEMM + al2 + output-linear: h3 = (out1@W2)@Wo ----------------
__global__ __launch_bounds__(256, 2) void k_gemm23(
    const ushort* __restrict__ A,    // out1 [NN][F1]
    const ushort* __restrict__ Bt,   // W2t  [F2][F1]
    const ushort* __restrict__ Wot,  // [F2][F2] ([n][k])
    ushort* __restrict__ h3,         // [NN][F2]
    const float* __restrict__ avs, const float* __restrict__ avd,
    float* __restrict__ out_s, float* __restrict__ out_d) {
    __shared__ __align__(16) char smem[69632];
    ushort (*As)[72]   = (ushort(*)[72])smem;              // [128][72]
    ushort (*Bs)[72]   = (ushort(*)[72])(smem + 18432);    // [128][72]
    ushort (*h2t)[136] = (ushort(*)[136])smem;             // [128][136]
    ushort (*Wt)[136]  = (ushort(*)[136])(smem + 34816);   // [128][136]
    __shared__ float als[2][128], ald[2][128];
    const int t    = threadIdx.x;
    const int lane = t & 63;
    const int w    = t >> 6;
    const int wr   = w >> 1, wc = w & 1;
    const int m0   = blockIdx.x * 128;
    floatx4 acc[4][4] = {};
    for (int k0 = 0; k0 < F1; k0 += 64) {
        #pragma unroll
        for (int p = 0; p < 4; ++p) {
            int linear = p * 2048 + t * 8;
            int row = linear >> 6;
            int col = linear & 63;
            short8 va = {};
            int gm = m0 + row;
            if (gm < NN) va = *(const short8*)(A + (size_t)gm * F1 + k0 + col);
            *(short8*)&As[row][col] = va;
            short8 vb = *(const short8*)(Bt + (size_t)row * F1 + k0 + col);
            *(short8*)&Bs[row][col] = vb;
        }
        __syncthreads();
        #pragma unroll
        for (int kk = 0; kk < 64; kk += 32) {
            const int q8 = (lane >> 4) * 8;
            short8 af[4], bf[4];
            #pragma unroll
            for (int i = 0; i < 4; ++i)
                af[i] = *(const short8*)&As[wr * 64 + i * 16 + (lane & 15)][kk + q8];
            #pragma unroll
            for (int j = 0; j < 4; ++j)
                bf[j] = *(const short8*)&Bs[wc * 64 + j * 16 + (lane & 15)][kk + q8];
            #pragma unroll
            for (int i = 0; i < 4; ++i)
                #pragma unroll
                for (int j = 0; j < 4; ++j)
                    acc[i][j] = __builtin_amdgcn_mfma_f32_16x16x32_bf16(
                        af[i], bf[j], acc[i][j], 0, 0, 0);
        }
        __syncthreads();
    }
    const int r0 = (lane >> 4) * 4;
    const int cc = lane & 15;
    {
        float as0 = avs[wc * 64 +  0 + cc], ad0 = avd[wc * 64 +  0 + cc];
        float as1 = avs[wc * 64 + 16 + cc], ad1 = avd[wc * 64 + 16 + cc];
        float as2 = avs[wc * 64 + 32 + cc], ad2 = avd[wc * 64 + 32 + cc];
        float as3 = avs[wc * 64 + 48 + cc], ad3 = avd[wc * 64 + 48 + cc];
        #pragma unroll
        for (int i = 0; i < 4; ++i) {
            #pragma unroll
            for (int r = 0; r < 4; ++r) {
                float ps = acc[i][0][r] * as0 + acc[i][1][r] * as1
                         + acc[i][2][r] * as2 + acc[i][3][r] * as3;
                float pd = acc[i][0][r] * ad0 + acc[i][1][r] * ad1
                         + acc[i][2][r] * ad2 + acc[i][3][r] * ad3;
                #pragma unroll
                for (int mask = 1; mask < 16; mask <<= 1) {
                    ps += __shfl_xor(ps, mask);
                    pd += __shfl_xor(pd, mask);
                }
                if (cc == 0) {
                    int lr = wr * 64 + i * 16 + r0 + r;
                    als[wc][lr] = ps;
                    ald[wc][lr] = pd;
                }
            }
        }
    }
    #pragma unroll
    for (int i = 0; i < 4; ++i)
        #pragma unroll
        for (int r = 0; r < 4; ++r)
            #pragma unroll
            for (int j = 0; j < 4; ++j)
                h2t[wr * 64 + i * 16 + r0 + r][wc * 64 + j * 16 + cc] = f2bf(acc[i][j][r]);
    #pragma unroll
    for (int p = 0; p < 8; ++p) {
        int linear = p * 2048 + t * 8;
        int row = linear >> 7;
        int col = linear & 127;
        *(short8*)&Wt[row][col] = *(const short8*)(Wot + (size_t)row * F2 + col);
    }
    __syncthreads();
    if (t < 128) {
        int m = m0 + t;
        if (m < NN) {
            out_s[m] = als[0][t] + als[1][t];
            out_d[m] = ald[0][t] + ald[1][t];
        }
    }
    floatx4 acc2[4][4] = {};
    #pragma unroll
    for (int kk = 0; kk < 128; kk += 32) {
        const int q8 = (lane >> 4) * 8;
        short8 af[4], bf[4];
        #pragma unroll
        for (int i = 0; i < 4; ++i)
            af[i] = *(const short8*)&h2t[wr * 64 + i * 16 + (lane & 15)][kk + q8];
        #pragma unroll
        for (int j = 0; j < 4; ++j)
            bf[j] = *(const short8*)&Wt[wc * 64 + j * 16 + (lane & 15)][kk + q8];
        #pragma unroll
        for (int i = 0; i < 4; ++i)
            #pragma unroll
            for (int j = 0; j < 4; ++j)
                acc2[i][j] = __builtin_amdgcn_mfma_f32_16x16x32_bf16(
                    af[i], bf[j], acc2[i][j], 0, 0, 0);
    }
    #pragma unroll
    for (int i = 0; i < 4; ++i) {
        #pragma unroll
        for (int r = 0; r < 4; ++r) {
            int m = m0 + wr * 64 + i * 16 + r0 + r;
            if (m < NN) {
                #pragma unroll
                for (int j = 0; j < 4; ++j)
                    h3[(size_t)m * F2 + wc * 64 + j * 16 + cc] = f2bf(acc2[i][j][r]);
            }
        }
    }
}

__device__ inline float lrelu(float x) { return x > 0.f ? x : 0.2f * x; }

// ---------------- GAT aggregation: 2 destinations per wave (32-lane sub-waves) ----------------
// agg1: channel phase uses ushort8 (16B) loads, 8 ch/lane; head = lane32>>2.
__global__ __launch_bounds__(256) void k_agg1(
    const int* __restrict__ offsets, const int* __restrict__ srcs,
    const ushort* __restrict__ h1, const float* __restrict__ a1s,
    const float* __restrict__ a1d, const float* __restrict__ b1,
    ushort* __restrict__ out1) {
    __shared__ float atab[8][512];   // [half-wave][edge*8+head], deg<=64
    __shared__ int   stab[8][64];
    const int hw = threadIdx.x >> 5;
    const int d  = blockIdx.x * 8 + hw;
    if (d >= NN) return;
    const int l   = threadIdx.x & 31;
    const int beg = offsets[d], end = offsets[d + 1];
    const int deg = end - beg;
    const int e4 = l >> 3, h8 = l & 7;
    const float ad = a1d[d * 8 + h8];
    const int hh = l >> 2;               // head for channel phase (8 ch/lane)
    float accv[8] = {};

    if (deg <= 64) {
        float m = -1e30f, den = 0.f;
        for (int e = e4; e < deg; e += 4) {
            int s = srcs[beg + e];
            if (h8 == 0) stab[hw][e] = s;
            float v = lrelu(a1s[s * 8 + h8] + ad);
            atab[hw][e * 8 + h8] = v;    // raw logit
            float nm = fmaxf(m, v);
            den = den * __expf(m - nm) + __expf(v - nm);
            m = nm;
        }
        #pragma unroll
        for (int mask = 8; mask < 32; mask <<= 1) {
            float om = __shfl_xor(m, mask);
            float od = __shfl_xor(den, mask);
            float nm = fmaxf(m, om);
            den = den * __expf(m - nm) + od * __expf(om - nm);
            m = nm;
        }
        float rden = 1.f / (den + 1e-16f);
        for (int p = l; p < deg * 8; p += 32)      // p&7 == h8
            atab[hw][p] = __expf(atab[hw][p] - m) * rden;
        int e = 0;
        for (; e + 4 <= deg; e += 4) {
            short8 u[4]; float a[4];
            #pragma unroll
            for (int jj = 0; jj < 4; ++jj) {
                int s = stab[hw][e + jj];
                u[jj] = *(const short8*)(h1 + (size_t)s * F1 + l * 8);
                a[jj] = atab[hw][(e + jj) * 8 + hh];
            }
            #pragma unroll
            for (int jj = 0; jj < 4; ++jj)
                #pragma unroll
                for (int c = 0; c < 8; ++c)
                    accv[c] += a[jj] * bf2f((ushort)u[jj][c]);
        }
        for (; e < deg; ++e) {
            int s = stab[hw][e];
            float alpha = atab[hw][e * 8 + hh];
            short8 u = *(const short8*)(h1 + (size_t)s * F1 + l * 8);
            #pragma unroll
            for (int c = 0; c < 8; ++c)
                accv[c] += alpha * bf2f((ushort)u[c]);
        }
    } else {
        // slow path (deg>64, ~never): 3-pass with 64-edge tiles
        float m = -1e30f, den = 0.f;
        for (int i = beg + e4; i < end; i += 4) {
            int s = srcs[i];
            float v = lrelu(a1s[s * 8 + h8] + ad);
            float nm = fmaxf(m, v);
            den = den * __expf(m - nm) + __expf(v - nm);
            m = nm;
        }
        #pragma unroll
        for (int mask = 8; mask < 32; mask <<= 1) {
            float om = __shfl_xor(m, mask);
            float od = __shfl_xor(den, mask);
            float nm = fmaxf(m, om);
            den = den * __expf(m - nm) + od * __expf(om - nm);
            m = nm;
        }
        float rden = 1.f / (den + 1e-16f);
        for (int tb = beg; tb < end; tb += 64) {
            int cnt = min(64, end - tb);
            for (int e = l; e < cnt; e += 32) stab[hw][e] = srcs[tb + e];
            for (int p = l; p < cnt * 8; p += 32) {
                int s = stab[hw][p >> 3];
                atab[hw][p] = __expf(lrelu(a1s[s * 8 + h8] + ad) - m) * rden;
            }
            for (int e = 0; e < cnt; ++e) {
                int s = stab[hw][e];
                float alpha = atab[hw][e * 8 + hh];
                short8 u = *(const short8*)(h1 + (size_t)s * F1 + l * 8);
                #pragma unroll
                for (int c = 0; c < 8; ++c)
                    accv[c] += alpha * bf2f((ushort)u[c]);
            }
        }
    }
    float4 bb0 = *(const float4*)(b1 + l * 8);
    float4 bb1 = *(const float4*)(b1 + l * 8 + 4);
    short8 o;
    o[0] = (short)f2bf(accv[0] + bb0.x); o[1] = (short)f2bf(accv[1] + bb0.y);
    o[2] = (short)f2bf(accv[2] + bb0.z); o[3] = (short)f2bf(accv[3] + bb0.w);
    o[4] = (short)f2bf(accv[4] + bb1.x); o[5] = (short)f2bf(accv[5] + bb1.y);
    o[6] = (short)f2bf(accv[6] + bb1.z); o[7] = (short)f2bf(accv[7] + bb1.w);
    *(short8*)(out1 + (size_t)d * F1 + l * 8) = o;
}

// agg2 over h3; writes FINAL fp32 out with bc = b2@Wo + bo. 2 dst/wave, 4 ch/lane.
__global__ __launch_bounds__(256) void k_agg2(
    const int* __restrict__ offsets, const int* __restrict__ srcs,
    const ushort* __restrict__ h3, const float* __restrict__ a2s,
    const float* __restrict__ a2d, const float* __restrict__ bc,
    float* __restrict__ out) {
    __shared__ float atab[8][64];
    __shared__ int   stab[8][64];
    const int hw = threadIdx.x >> 5;
    const int d  = blockIdx.x * 8 + hw;
    if (d >= NN) return;
    const int l   = threadIdx.x & 31;
    const int beg = offsets[d], end = offsets[d + 1];
    const int deg = end - beg;
    const float ad = a2d[d];
    float accv[4] = {};

    if (deg <= 64) {
        float m = -1e30f, den = 0.f;
        for (int e = l; e < deg; e += 32) {
            int s = srcs[beg + e];
            stab[hw][e] = s;
            float v = lrelu(a2s[s] + ad);
            atab[hw][e] = v;
            float nm = fmaxf(m, v);
            den = den * __expf(m - nm) + __expf(v - nm);
            m = nm;
        }
        #pragma unroll
        for (int mask = 1; mask < 32; mask <<= 1) {
            float om = __shfl_xor(m, mask);
            float od = __shfl_xor(den, mask);
            float nm = fmaxf(m, om);
            den = den * __expf(m - nm) + od * __expf(om - nm);
            m = nm;
        }
        float rden = 1.f / (den + 1e-16f);
        for (int p = l; p < deg; p += 32)
            atab[hw][p] = __expf(atab[hw][p] - m) * rden;
        int e = 0;
        for (; e + 8 <= deg; e += 8) {
            ushort4 u[8]; float a[8];
            #pragma unroll
            for (int jj = 0; jj < 8; ++jj) {
                int s = stab[hw][e + jj];
                u[jj] = *(const ushort4*)(h3 + (size_t)s * F2 + l * 4);
                a[jj] = atab[hw][e + jj];
            }
            #pragma unroll
            for (int jj = 0; jj < 8; ++jj) {
                accv[0] += a[jj] * bf2f(u[jj].x);
                accv[1] += a[jj] * bf2f(u[jj].y);
                accv[2] += a[jj] * bf2f(u[jj].z);
                accv[3] += a[jj] * bf2f(u[jj].w);
            }
        }
        for (; e < deg; ++e) {
            int s = stab[hw][e];
            float alpha = atab[hw][e];
            ushort4 u = *(const ushort4*)(h3 + (size_t)s * F2 + l * 4);
            accv[0] += alpha * bf2f(u.x); accv[1] += alpha * bf2f(u.y);
            accv[2] += alpha * bf2f(u.z); accv[3] += alpha * bf2f(u.w);
        }
    } else {
        float m = -1e30f, den = 0.f;
        for (int i = beg + l; i < end; i += 32) {
            int s = srcs[i];
            float v = lrelu(a2s[s] + ad);
            float nm = fmaxf(m, v);
            den = den * __expf(m - nm) + __expf(v - nm);
            m = nm;
        }
        #pragma unroll
        for (int mask = 1; mask < 32; mask <<= 1) {
            float om = __shfl_xor(m, mask);
            float od = __shfl_xor(den, mask);
            float nm = fmaxf(m, om);
            den = den * __expf(m - nm) + od * __expf(om - nm);
            m = nm;
        }
        float rden = 1.f / (den + 1e-16f);
        for (int tb = beg; tb < end; tb += 64) {
            int cnt = min(64, end - tb);
            for (int e = l; e < cnt; e += 32) {
                int s = srcs[tb + e];
                stab[hw][e] = s;
                atab[hw][e] = __expf(lrelu(a2s[s] + ad) - m) * rden;
            }
            for (int e = 0; e < cnt; ++e) {
                int s = stab[hw][e];
                float alpha = atab[hw][e];
                ushort4 u = *(const ushort4*)(h3 + (size_t)s * F2 + l * 4);
                accv[0] += alpha * bf2f(u.x); accv[1] += alpha * bf2f(u.y);
                accv[2] += alpha * bf2f(u.z); accv[3] += alpha * bf2f(u.w);
            }
        }
    }
    float4 bb = *(const float4*)(bc + l * 4);
    float4 o = make_float4(accv[0] + bb.x, accv[1] + bb.y, accv[2] + bb.z, accv[3] + bb.w);
    *(float4*)(out + (size_t)d * F2 + l * 4) = o;
}

extern "C" void kernel_launch(void* const* d_in, const int* in_sizes, int n_in,
                              void* d_out, int out_size, void* d_ws, size_t ws_size,
                              hipStream_t stream) {
    const int*   x      = (const int*)d_in[0];
    const int*   edge   = (const int*)d_in[1];   // [2][E]
    const float* emb    = (const float*)d_in[2];
    const float* W1     = (const float*)d_in[3];
    const float* a_src1 = (const float*)d_in[4];
    const float* a_dst1 = (const float*)d_in[5];
    const float* b1     = (const float*)d_in[6];
    const float* W2     = (const float*)d_in[7];
    const float* a_src2 = (const float*)d_in[8];
    const float* a_dst2 = (const float*)d_in[9];
    const float* b2     = (const float*)d_in[10];
    const float* Wo     = (const float*)d_in[11];
    const float* bo     = (const float*)d_in[12];
    float* out = (float*)d_out;

    char* w = (char*)d_ws;
    auto alloc = [&](size_t bytes) {
        char* p = w;
        w += (bytes + 255) & ~(size_t)255;
        return p;
    };
    int*    offsets = (int*)alloc((NN + 1) * sizeof(int));
    int*    cnt     = (int*)alloc(NN * sizeof(int));
    int*    sums    = (int*)alloc(256 * sizeof(int));
    int*    srcs    = (int*)alloc((size_t)(EE + NN) * sizeof(int));
    ushort* W1t     = (ushort*)alloc((size_t)DD * F1 * sizeof(ushort));
    ushort* W2t     = (ushort*)alloc((size_t)F1 * F2 * sizeof(ushort));
    ushort* Wot     = (ushort*)alloc((size_t)F2 * F2 * sizeof(ushort));
    ushort* h1      = (ushort*)alloc((size_t)NN * F1 * sizeof(ushort));
    ushort* out1    = (ushort*)alloc((size_t)NN * F1 * sizeof(ushort));
    ushort* h3      = (ushort*)alloc((size_t)NN * F2 * sizeof(ushort));
    float*  a1s     = (float*)alloc((size_t)NN * 8 * sizeof(float));
    float*  a1d     = (float*)alloc((size_t)NN * 8 * sizeof(float));
    float*  bc      = (float*)alloc(F2 * sizeof(float));
    float*  a2s     = a1s;
    float*  a2d     = a1d;

    const int* esrc = edge;
    const int* edst = edge + EE;

    // cooperative fused CSR build + weight converts (1 dispatch, 256 co-resident blocks)
    {
        void* args[] = {
            (void*)&esrc, (void*)&edst, (void*)&cnt, (void*)&offsets, (void*)&sums,
            (void*)&srcs, (void*)&W1, (void*)&W1t, (void*)&W2, (void*)&W2t,
            (void*)&Wo, (void*)&Wot, (void*)&b2, (void*)&bo, (void*)&bc
        };
        hipLaunchCooperativeKernel((void*)k_build, dim3(256), dim3(256), args, 0, stream);
    }

    const int MT = (NN + 127) / 128;        // 391

    // conv1 (GEMM + fused emb gather + al1)
    k_gemm1<<<dim3(MT, F1 / 128), 256, 0, stream>>>(
        x, emb, W1t, h1, a_src1, a_dst1, a1s, a1d);
    k_agg1<<<(NN + 7) / 8, 256, 0, stream>>>(offsets, srcs, h1, a1s, a1d, b1, out1);

    // conv2 GEMM + al2 + output linear fused: h3 = (out1@W2)@Wo
    k_gemm23<<<dim3(MT, 1), 256, 0, stream>>>(
        out1, W2t, Wot, h3, a_src2, a_dst2, a2s, a2d);

    // final aggregation writes fp32 out directly
    k_agg2<<<(NN + 7) / 8, 256, 0, stream>>>(offsets, srcs, h3, a2s, a2d, bc, out);
}

// Round 11
// 343.218 us; speedup vs baseline: 1.3518x; 1.3518x over previous
//
#include <hip/hip_runtime.h>
#include <hip/hip_bf16.h>

#define NN 50000
#define EE 800000
#define DD 128
#define F1 256   // H*HID after conv1
#define F2 128   // OUT

using short8  = __attribute__((ext_vector_type(8))) short;
using floatx4 = __attribute__((ext_vector_type(4))) float;

__device__ inline float bf2f(ushort u) { return __uint_as_float(((unsigned)u) << 16); }
__device__ inline ushort f2bf(float f) {
    unsigned u = __float_as_uint(f);
    u += 0x7fffu + ((u >> 16) & 1u);      // round-to-nearest-even
    return (ushort)(u >> 16);
}

// ---------------- fused prep: edge histogram + weight transposes + bc ----------------
#define HB ((EE + 255) / 256)          // 3125
#define W1B ((DD * F1 + 255) / 256)    // 128
#define W2B ((F1 * F2 + 255) / 256)    // 128
#define WOB ((F2 * F2 + 255) / 256)    // 64

__global__ __launch_bounds__(256) void k_prep(
    const int* __restrict__ edst, int* __restrict__ cnt,
    const float* __restrict__ W1, ushort* __restrict__ W1t,
    const float* __restrict__ W2, ushort* __restrict__ W2t,
    const float* __restrict__ Wo, ushort* __restrict__ Wot,
    const float* __restrict__ b2, const float* __restrict__ bo,
    float* __restrict__ bc) {
    int b = blockIdx.x;
    if (b < HB) {
        int i = b * 256 + threadIdx.x;
        if (i < EE) atomicAdd(&cnt[edst[i]], 1);
    } else if (b < HB + W1B) {
        int idx = (b - HB) * 256 + threadIdx.x;
        int k = idx / F1, n = idx % F1;
        W1t[(size_t)n * DD + k] = f2bf(W1[(size_t)k * F1 + n]);
    } else if (b < HB + W1B + W2B) {
        int idx = (b - HB - W1B) * 256 + threadIdx.x;
        int k = idx / F2, n = idx % F2;
        W2t[(size_t)n * F1 + k] = f2bf(W2[(size_t)k * F2 + n]);
    } else if (b < HB + W1B + W2B + WOB) {
        int idx = (b - HB - W1B - W2B) * 256 + threadIdx.x;
        int k = idx / F2, n = idx % F2;
        Wot[(size_t)n * F2 + k] = f2bf(Wo[(size_t)k * F2 + n]);
    } else {
        int j = threadIdx.x;
        if (j < F2) {
            float s = bo[j];
            for (int k = 0; k < F2; ++k) s += b2[k] * Wo[(size_t)k * F2 + j];
            bc[j] = s;
        }
    }
}

// ---------------- CSR scan + scatter ----------------
__global__ void k_scan1(const int* __restrict__ cnt, int* __restrict__ out,
                        int* __restrict__ sums) {
    __shared__ int s[256];
    int i = blockIdx.x * 256 + threadIdx.x;
    int v = (i < NN) ? cnt[i] + 1 : 0;   // +1 self-loop
    s[threadIdx.x] = v;
    __syncthreads();
    for (int off = 1; off < 256; off <<= 1) {
        int t = (threadIdx.x >= off) ? s[threadIdx.x - off] : 0;
        __syncthreads();
        s[threadIdx.x] += t;
        __syncthreads();
    }
    if (i < NN) out[i] = s[threadIdx.x] - v;   // exclusive
    if (threadIdx.x == 255) sums[blockIdx.x] = s[255];
}

__global__ void k_scan3(int* __restrict__ offsets, const int* __restrict__ sums,
                        int* __restrict__ cursor, int nb) {
    __shared__ int s[256];
    int v = (threadIdx.x < nb) ? sums[threadIdx.x] : 0;
    s[threadIdx.x] = v;
    __syncthreads();
    for (int off = 1; off < 256; off <<= 1) {
        int t = (threadIdx.x >= off) ? s[threadIdx.x - off] : 0;
        __syncthreads();
        s[threadIdx.x] += t;
        __syncthreads();
    }
    int base = (blockIdx.x == 0) ? 0 : s[blockIdx.x - 1];
    int i = blockIdx.x * 256 + threadIdx.x;
    if (i < NN) {
        int o = offsets[i] + base;
        offsets[i] = o;
        cursor[i] = o;
    }
    if (blockIdx.x == 0 && threadIdx.x == 0) offsets[NN] = EE + NN;
}

// edges via atomic cursor; self-loop deterministically at offsets[n+1]-1 (no atomic).
__global__ void k_scatter(const int* __restrict__ esrc, const int* __restrict__ edst,
                          const int* __restrict__ offsets,
                          int* __restrict__ cursor, int* __restrict__ srcs) {
    int i = blockIdx.x * 256 + threadIdx.x;
    if (i < EE) {
        int pos = atomicAdd(&cursor[edst[i]], 1);
        srcs[pos] = esrc[i];
    } else if (i < EE + NN) {
        int n = i - EE;
        srcs[offsets[n + 1] - 1] = n;
    }
}

// ---------------- conv1 GEMM (128x128 tile) + fused emb-gather + 8-head logits ----------------
__global__ __launch_bounds__(256, 2) void k_gemm1(
    const int* __restrict__ x, const float* __restrict__ emb,
    const ushort* __restrict__ Bt,
    ushort* __restrict__ Cout,
    const float* __restrict__ avs, const float* __restrict__ avd,
    float* __restrict__ out_s, float* __restrict__ out_d) {
    __shared__ ushort As[128][72];   // [m][k]
    __shared__ ushort Bs[128][72];   // [n][k]
    const int t    = threadIdx.x;
    const int lane = t & 63;
    const int w    = t >> 6;
    const int wr   = w >> 1, wc = w & 1;
    const int m0   = blockIdx.x * 128;
    const int n0   = blockIdx.y * 128;
    floatx4 acc[4][4] = {};
    for (int k0 = 0; k0 < DD; k0 += 64) {
        #pragma unroll
        for (int p = 0; p < 4; ++p) {
            int linear = p * 2048 + t * 8;
            int row = linear >> 6;
            int col = linear & 63;
            short8 va = {};
            int gm = m0 + row;
            if (gm < NN) {
                const float* er = emb + (size_t)x[gm] * DD + k0 + col;
                float4 f0 = *(const float4*)er;
                float4 f1 = *(const float4*)(er + 4);
                va[0] = f2bf(f0.x); va[1] = f2bf(f0.y);
                va[2] = f2bf(f0.z); va[3] = f2bf(f0.w);
                va[4] = f2bf(f1.x); va[5] = f2bf(f1.y);
                va[6] = f2bf(f1.z); va[7] = f2bf(f1.w);
            }
            *(short8*)&As[row][col] = va;
            short8 vb = *(const short8*)(Bt + (size_t)(n0 + row) * DD + k0 + col);
            *(short8*)&Bs[row][col] = vb;
        }
        __syncthreads();
        #pragma unroll
        for (int kk = 0; kk < 64; kk += 32) {
            const int q8 = (lane >> 4) * 8;
            short8 af[4], bf[4];
            #pragma unroll
            for (int i = 0; i < 4; ++i)
                af[i] = *(const short8*)&As[wr * 64 + i * 16 + (lane & 15)][kk + q8];
            #pragma unroll
            for (int j = 0; j < 4; ++j)
                bf[j] = *(const short8*)&Bs[wc * 64 + j * 16 + (lane & 15)][kk + q8];
            #pragma unroll
            for (int i = 0; i < 4; ++i)
                #pragma unroll
                for (int j = 0; j < 4; ++j)
                    acc[i][j] = __builtin_amdgcn_mfma_f32_16x16x32_bf16(
                        af[i], bf[j], acc[i][j], 0, 0, 0);
        }
        __syncthreads();
    }
    const int r0 = (lane >> 4) * 4;
    const int cc = lane & 15;
    float as0 = avs[n0 + wc * 64 +  0 + cc], ad0 = avd[n0 + wc * 64 +  0 + cc];
    float as1 = avs[n0 + wc * 64 + 16 + cc], ad1 = avd[n0 + wc * 64 + 16 + cc];
    float as2 = avs[n0 + wc * 64 + 32 + cc], ad2 = avd[n0 + wc * 64 + 32 + cc];
    float as3 = avs[n0 + wc * 64 + 48 + cc], ad3 = avd[n0 + wc * 64 + 48 + cc];
    #pragma unroll
    for (int i = 0; i < 4; ++i) {
        #pragma unroll
        for (int r = 0; r < 4; ++r) {
            int m = m0 + wr * 64 + i * 16 + r0 + r;
            float hs0 = acc[i][0][r] * as0 + acc[i][1][r] * as1;
            float hs1 = acc[i][2][r] * as2 + acc[i][3][r] * as3;
            float hd0 = acc[i][0][r] * ad0 + acc[i][1][r] * ad1;
            float hd1 = acc[i][2][r] * ad2 + acc[i][3][r] * ad3;
            #pragma unroll
            for (int mask = 1; mask < 16; mask <<= 1) {
                hs0 += __shfl_xor(hs0, mask);
                hs1 += __shfl_xor(hs1, mask);
                hd0 += __shfl_xor(hd0, mask);
                hd1 += __shfl_xor(hd1, mask);
            }
            if (cc == 0 && m < NN) {
                int gh = (n0 >> 5) + wc * 2;
                out_s[m * 8 + gh] = hs0;   out_s[m * 8 + gh + 1] = hs1;
                out_d[m * 8 + gh] = hd0;   out_d[m * 8 + gh + 1] = hd1;
            }
            if (m < NN) {
                #pragma unroll
                for (int j = 0; j < 4; ++j)
                    Cout[(size_t)m * F1 + n0 + wc * 64 + j * 16 + cc] = f2bf(acc[i][j][r]);
            }
        }
    }
}

// ---------------- fused conv2 GEMM + al2 + output-linear: h3 = (out1@W2)@Wo ----------------
__global__ __launch_bounds__(256, 2) void k_gemm23(
    const ushort* __restrict__ A,    // out1 [NN][F1]
    const ushort* __restrict__ Bt,   // W2t  [F2][F1]
    const ushort* __restrict__ Wot,  // [F2][F2] ([n][k])
    ushort* __restrict__ h3,         // [NN][F2]
    const float* __restrict__ avs, const float* __restrict__ avd,
    float* __restrict__ out_s, float* __restrict__ out_d) {
    __shared__ __align__(16) char smem[69632];
    ushort (*As)[72]   = (ushort(*)[72])smem;              // [128][72]
    ushort (*Bs)[72]   = (ushort(*)[72])(smem + 18432);    // [128][72]
    ushort (*h2t)[136] = (ushort(*)[136])smem;             // [128][136]
    ushort (*Wt)[136]  = (ushort(*)[136])(smem + 34816);   // [128][136]
    __shared__ float als[2][128], ald[2][128];
    const int t    = threadIdx.x;
    const int lane = t & 63;
    const int w    = t >> 6;
    const int wr   = w >> 1, wc = w & 1;
    const int m0   = blockIdx.x * 128;
    floatx4 acc[4][4] = {};
    for (int k0 = 0; k0 < F1; k0 += 64) {
        #pragma unroll
        for (int p = 0; p < 4; ++p) {
            int linear = p * 2048 + t * 8;
            int row = linear >> 6;
            int col = linear & 63;
            short8 va = {};
            int gm = m0 + row;
            if (gm < NN) va = *(const short8*)(A + (size_t)gm * F1 + k0 + col);
            *(short8*)&As[row][col] = va;
            short8 vb = *(const short8*)(Bt + (size_t)row * F1 + k0 + col);
            *(short8*)&Bs[row][col] = vb;
        }
        __syncthreads();
        #pragma unroll
        for (int kk = 0; kk < 64; kk += 32) {
            const int q8 = (lane >> 4) * 8;
            short8 af[4], bf[4];
            #pragma unroll
            for (int i = 0; i < 4; ++i)
                af[i] = *(const short8*)&As[wr * 64 + i * 16 + (lane & 15)][kk + q8];
            #pragma unroll
            for (int j = 0; j < 4; ++j)
                bf[j] = *(const short8*)&Bs[wc * 64 + j * 16 + (lane & 15)][kk + q8];
            #pragma unroll
            for (int i = 0; i < 4; ++i)
                #pragma unroll
                for (int j = 0; j < 4; ++j)
                    acc[i][j] = __builtin_amdgcn_mfma_f32_16x16x32_bf16(
                        af[i], bf[j], acc[i][j], 0, 0, 0);
        }
        __syncthreads();
    }
    const int r0 = (lane >> 4) * 4;
    const int cc = lane & 15;
    {
        float as0 = avs[wc * 64 +  0 + cc], ad0 = avd[wc * 64 +  0 + cc];
        float as1 = avs[wc * 64 + 16 + cc], ad1 = avd[wc * 64 + 16 + cc];
        float as2 = avs[wc * 64 + 32 + cc], ad2 = avd[wc * 64 + 32 + cc];
        float as3 = avs[wc * 64 + 48 + cc], ad3 = avd[wc * 64 + 48 + cc];
        #pragma unroll
        for (int i = 0; i < 4; ++i) {
            #pragma unroll
            for (int r = 0; r < 4; ++r) {
                float ps = acc[i][0][r] * as0 + acc[i][1][r] * as1
                         + acc[i][2][r] * as2 + acc[i][3][r] * as3;
                float pd = acc[i][0][r] * ad0 + acc[i][1][r] * ad1
                         + acc[i][2][r] * ad2 + acc[i][3][r] * ad3;
                #pragma unroll
                for (int mask = 1; mask < 16; mask <<= 1) {
                    ps += __shfl_xor(ps, mask);
                    pd += __shfl_xor(pd, mask);
                }
                if (cc == 0) {
                    int lr = wr * 64 + i * 16 + r0 + r;
                    als[wc][lr] = ps;
                    ald[wc][lr] = pd;
                }
            }
        }
    }
    #pragma unroll
    for (int i = 0; i < 4; ++i)
        #pragma unroll
        for (int r = 0; r < 4; ++r)
            #pragma unroll
            for (int j = 0; j < 4; ++j)
                h2t[wr * 64 + i * 16 + r0 + r][wc * 64 + j * 16 + cc] = f2bf(acc[i][j][r]);
    #pragma unroll
    for (int p = 0; p < 8; ++p) {
        int linear = p * 2048 + t * 8;
        int row = linear >> 7;
        int col = linear & 127;
        *(short8*)&Wt[row][col] = *(const short8*)(Wot + (size_t)row * F2 + col);
    }
    __syncthreads();
    if (t < 128) {
        int m = m0 + t;
        if (m < NN) {
            out_s[m] = als[0][t] + als[1][t];
            out_d[m] = ald[0][t] + ald[1][t];
        }
    }
    floatx4 acc2[4][4] = {};
    #pragma unroll
    for (int kk = 0; kk < 128; kk += 32) {
        const int q8 = (lane >> 4) * 8;
        short8 af[4], bf[4];
        #pragma unroll
        for (int i = 0; i < 4; ++i)
            af[i] = *(const short8*)&h2t[wr * 64 + i * 16 + (lane & 15)][kk + q8];
        #pragma unroll
        for (int j = 0; j < 4; ++j)
            bf[j] = *(const short8*)&Wt[wc * 64 + j * 16 + (lane & 15)][kk + q8];
        #pragma unroll
        for (int i = 0; i < 4; ++i)
            #pragma unroll
            for (int j = 0; j < 4; ++j)
                acc2[i][j] = __builtin_amdgcn_mfma_f32_16x16x32_bf16(
                    af[i], bf[j], acc2[i][j], 0, 0, 0);
    }
    #pragma unroll
    for (int i = 0; i < 4; ++i) {
        #pragma unroll
        for (int r = 0; r < 4; ++r) {
            int m = m0 + wr * 64 + i * 16 + r0 + r;
            if (m < NN) {
                #pragma unroll
                for (int j = 0; j < 4; ++j)
                    h3[(size_t)m * F2 + wc * 64 + j * 16 + cc] = f2bf(acc2[i][j][r]);
            }
        }
    }
}

__device__ inline float lrelu(float x) { return x > 0.f ? x : 0.2f * x; }

// ---------------- GAT aggregation: 2 destinations per wave (32-lane sub-waves) ----------------
__global__ __launch_bounds__(256) void k_agg1(
    const int* __restrict__ offsets, const int* __restrict__ srcs,
    const ushort* __restrict__ h1, const float* __restrict__ a1s,
    const float* __restrict__ a1d, const float* __restrict__ b1,
    ushort* __restrict__ out1) {
    __shared__ float atab[8][512];   // [half-wave][edge*8+head], deg<=64
    __shared__ int   stab[8][64];
    const int hw = threadIdx.x >> 5;
    const int d  = blockIdx.x * 8 + hw;
    if (d >= NN) return;
    const int l   = threadIdx.x & 31;
    const int beg = offsets[d], end = offsets[d + 1];
    const int deg = end - beg;
    const int e4 = l >> 3, h8 = l & 7;
    const float ad = a1d[d * 8 + h8];
    const int hh = l >> 2;               // head for channel phase (8 ch/lane)
    float accv[8] = {};

    if (deg <= 64) {
        float m = -1e30f, den = 0.f;
        for (int e = e4; e < deg; e += 4) {
            int s = srcs[beg + e];
            if (h8 == 0) stab[hw][e] = s;
            float v = lrelu(a1s[s * 8 + h8] + ad);
            atab[hw][e * 8 + h8] = v;    // raw logit
            float nm = fmaxf(m, v);
            den = den * __expf(m - nm) + __expf(v - nm);
            m = nm;
        }
        #pragma unroll
        for (int mask = 8; mask < 32; mask <<= 1) {
            float om = __shfl_xor(m, mask);
            float od = __shfl_xor(den, mask);
            float nm = fmaxf(m, om);
            den = den * __expf(m - nm) + od * __expf(om - nm);
            m = nm;
        }
        float rden = 1.f / (den + 1e-16f);
        for (int p = l; p < deg * 8; p += 32)      // p&7 == h8
            atab[hw][p] = __expf(atab[hw][p] - m) * rden;
        int e = 0;
        for (; e + 4 <= deg; e += 4) {
            short8 u[4]; float a[4];
            #pragma unroll
            for (int jj = 0; jj < 4; ++jj) {
                int s = stab[hw][e + jj];
                u[jj] = *(const short8*)(h1 + (size_t)s * F1 + l * 8);
                a[jj] = atab[hw][(e + jj) * 8 + hh];
            }
            #pragma unroll
            for (int jj = 0; jj < 4; ++jj)
                #pragma unroll
                for (int c = 0; c < 8; ++c)
                    accv[c] += a[jj] * bf2f((ushort)u[jj][c]);
        }
        for (; e < deg; ++e) {
            int s = stab[hw][e];
            float alpha = atab[hw][e * 8 + hh];
            short8 u = *(const short8*)(h1 + (size_t)s * F1 + l * 8);
            #pragma unroll
            for (int c = 0; c < 8; ++c)
                accv[c] += alpha * bf2f((ushort)u[c]);
        }
    } else {
        float m = -1e30f, den = 0.f;
        for (int i = beg + e4; i < end; i += 4) {
            int s = srcs[i];
            float v = lrelu(a1s[s * 8 + h8] + ad);
            float nm = fmaxf(m, v);
            den = den * __expf(m - nm) + __expf(v - nm);
            m = nm;
        }
        #pragma unroll
        for (int mask = 8; mask < 32; mask <<= 1) {
            float om = __shfl_xor(m, mask);
            float od = __shfl_xor(den, mask);
            float nm = fmaxf(m, om);
            den = den * __expf(m - nm) + od * __expf(om - nm);
            m = nm;
        }
        float rden = 1.f / (den + 1e-16f);
        for (int tb = beg; tb < end; tb += 64) {
            int cnt = min(64, end - tb);
            for (int e = l; e < cnt; e += 32) stab[hw][e] = srcs[tb + e];
            for (int p = l; p < cnt * 8; p += 32) {
                int s = stab[hw][p >> 3];
                atab[hw][p] = __expf(lrelu(a1s[s * 8 + h8] + ad) - m) * rden;
            }
            for (int e = 0; e < cnt; ++e) {
                int s = stab[hw][e];
                float alpha = atab[hw][e * 8 + hh];
                short8 u = *(const short8*)(h1 + (size_t)s * F1 + l * 8);
                #pragma unroll
                for (int c = 0; c < 8; ++c)
                    accv[c] += alpha * bf2f((ushort)u[c]);
            }
        }
    }
    float4 bb0 = *(const float4*)(b1 + l * 8);
    float4 bb1 = *(const float4*)(b1 + l * 8 + 4);
    short8 o;
    o[0] = (short)f2bf(accv[0] + bb0.x); o[1] = (short)f2bf(accv[1] + bb0.y);
    o[2] = (short)f2bf(accv[2] + bb0.z); o[3] = (short)f2bf(accv[3] + bb0.w);
    o[4] = (short)f2bf(accv[4] + bb1.x); o[5] = (short)f2bf(accv[5] + bb1.y);
    o[6] = (short)f2bf(accv[6] + bb1.z); o[7] = (short)f2bf(accv[7] + bb1.w);
    *(short8*)(out1 + (size_t)d * F1 + l * 8) = o;
}

// agg2 over h3; writes FINAL fp32 out with bc = b2@Wo + bo. 2 dst/wave, 4 ch/lane.
__global__ __launch_bounds__(256) void k_agg2(
    const int* __restrict__ offsets, const int* __restrict__ srcs,
    const ushort* __restrict__ h3, const float* __restrict__ a2s,
    const float* __restrict__ a2d, const float* __restrict__ bc,
    float* __restrict__ out) {
    __shared__ float atab[8][64];
    __shared__ int   stab[8][64];
    const int hw = threadIdx.x >> 5;
    const int d  = blockIdx.x * 8 + hw;
    if (d >= NN) return;
    const int l   = threadIdx.x & 31;
    const int beg = offsets[d], end = offsets[d + 1];
    const int deg = end - beg;
    const float ad = a2d[d];
    float accv[4] = {};

    if (deg <= 64) {
        float m = -1e30f, den = 0.f;
        for (int e = l; e < deg; e += 32) {
            int s = srcs[beg + e];
            stab[hw][e] = s;
            float v = lrelu(a2s[s] + ad);
            atab[hw][e] = v;
            float nm = fmaxf(m, v);
            den = den * __expf(m - nm) + __expf(v - nm);
            m = nm;
        }
        #pragma unroll
        for (int mask = 1; mask < 32; mask <<= 1) {
            float om = __shfl_xor(m, mask);
            float od = __shfl_xor(den, mask);
            float nm = fmaxf(m, om);
            den = den * __expf(m - nm) + od * __expf(om - nm);
            m = nm;
        }
        float rden = 1.f / (den + 1e-16f);
        for (int p = l; p < deg; p += 32)
            atab[hw][p] = __expf(atab[hw][p] - m) * rden;
        int e = 0;
        for (; e + 8 <= deg; e += 8) {
            ushort4 u[8]; float a[8];
            #pragma unroll
            for (int jj = 0; jj < 8; ++jj) {
                int s = stab[hw][e + jj];
                u[jj] = *(const ushort4*)(h3 + (size_t)s * F2 + l * 4);
                a[jj] = atab[hw][e + jj];
            }
            #pragma unroll
            for (int jj = 0; jj < 8; ++jj) {
                accv[0] += a[jj] * bf2f(u[jj].x);
                accv[1] += a[jj] * bf2f(u[jj].y);
                accv[2] += a[jj] * bf2f(u[jj].z);
                accv[3] += a[jj] * bf2f(u[jj].w);
            }
        }
        for (; e < deg; ++e) {
            int s = stab[hw][e];
            float alpha = atab[hw][e];
            ushort4 u = *(const ushort4*)(h3 + (size_t)s * F2 + l * 4);
            accv[0] += alpha * bf2f(u.x); accv[1] += alpha * bf2f(u.y);
            accv[2] += alpha * bf2f(u.z); accv[3] += alpha * bf2f(u.w);
        }
    } else {
        float m = -1e30f, den = 0.f;
        for (int i = beg + l; i < end; i += 32) {
            int s = srcs[i];
            float v = lrelu(a2s[s] + ad);
            float nm = fmaxf(m, v);
            den = den * __expf(m - nm) + __expf(v - nm);
            m = nm;
        }
        #pragma unroll
        for (int mask = 1; mask < 32; mask <<= 1) {
            float om = __shfl_xor(m, mask);
            float od = __shfl_xor(den, mask);
            float nm = fmaxf(m, om);
            den = den * __expf(m - nm) + od * __expf(om - nm);
            m = nm;
        }
        float rden = 1.f / (den + 1e-16f);
        for (int tb = beg; tb < end; tb += 64) {
            int cnt = min(64, end - tb);
            for (int e = l; e < cnt; e += 32) {
                int s = srcs[tb + e];
                stab[hw][e] = s;
                atab[hw][e] = __expf(lrelu(a2s[s] + ad) - m) * rden;
            }
            for (int e = 0; e < cnt; ++e) {
                int s = stab[hw][e];
                float alpha = atab[hw][e];
                ushort4 u = *(const ushort4*)(h3 + (size_t)s * F2 + l * 4);
                accv[0] += alpha * bf2f(u.x); accv[1] += alpha * bf2f(u.y);
                accv[2] += alpha * bf2f(u.z); accv[3] += alpha * bf2f(u.w);
            }
        }
    }
    float4 bb = *(const float4*)(bc + l * 4);
    float4 o = make_float4(accv[0] + bb.x, accv[1] + bb.y, accv[2] + bb.z, accv[3] + bb.w);
    *(float4*)(out + (size_t)d * F2 + l * 4) = o;
}

extern "C" void kernel_launch(void* const* d_in, const int* in_sizes, int n_in,
                              void* d_out, int out_size, void* d_ws, size_t ws_size,
                              hipStream_t stream) {
    const int*   x      = (const int*)d_in[0];
    const int*   edge   = (const int*)d_in[1];   // [2][E]
    const float* emb    = (const float*)d_in[2];
    const float* W1     = (const float*)d_in[3];
    const float* a_src1 = (const float*)d_in[4];
    const float* a_dst1 = (const float*)d_in[5];
    const float* b1     = (const float*)d_in[6];
    const float* W2     = (const float*)d_in[7];
    const float* a_src2 = (const float*)d_in[8];
    const float* a_dst2 = (const float*)d_in[9];
    const float* b2     = (const float*)d_in[10];
    const float* Wo     = (const float*)d_in[11];
    const float* bo     = (const float*)d_in[12];
    float* out = (float*)d_out;

    char* w = (char*)d_ws;
    auto alloc = [&](size_t bytes) {
        char* p = w;
        w += (bytes + 255) & ~(size_t)255;
        return p;
    };
    int*    offsets = (int*)alloc((NN + 1) * sizeof(int));
    int*    cursor  = (int*)alloc(NN * sizeof(int));
    int*    sums    = (int*)alloc(256 * sizeof(int));
    int*    srcs    = (int*)alloc((size_t)(EE + NN) * sizeof(int));
    ushort* W1t     = (ushort*)alloc((size_t)DD * F1 * sizeof(ushort));
    ushort* W2t     = (ushort*)alloc((size_t)F1 * F2 * sizeof(ushort));
    ushort* Wot     = (ushort*)alloc((size_t)F2 * F2 * sizeof(ushort));
    ushort* h1      = (ushort*)alloc((size_t)NN * F1 * sizeof(ushort));
    ushort* out1    = (ushort*)alloc((size_t)NN * F1 * sizeof(ushort));
    ushort* h3      = (ushort*)alloc((size_t)NN * F2 * sizeof(ushort));
    float*  a1s     = (float*)alloc((size_t)NN * 8 * sizeof(float));
    float*  a1d     = (float*)alloc((size_t)NN * 8 * sizeof(float));
    float*  bc      = (float*)alloc(F2 * sizeof(float));
    float*  a2s     = a1s;
    float*  a2d     = a1d;

    const int* esrc = edge;
    const int* edst = edge + EE;

    const int NB = (NN + 255) / 256;        // 196

    // CSR build + weight converts
    hipMemsetAsync(cursor, 0, NN * sizeof(int), stream);
    k_prep<<<HB + W1B + W2B + WOB + 1, 256, 0, stream>>>(
        edst, cursor, W1, W1t, W2, W2t, Wo, Wot, b2, bo, bc);
    k_scan1<<<NB, 256, 0, stream>>>(cursor, offsets, sums);
    k_scan3<<<NB, 256, 0, stream>>>(offsets, sums, cursor, NB);
    k_scatter<<<(EE + NN + 255) / 256, 256, 0, stream>>>(esrc, edst, offsets, cursor, srcs);

    const int MT = (NN + 127) / 128;        // 391

    // conv1 (GEMM + fused emb gather + al1)
    k_gemm1<<<dim3(MT, F1 / 128), 256, 0, stream>>>(
        x, emb, W1t, h1, a_src1, a_dst1, a1s, a1d);
    k_agg1<<<(NN + 7) / 8, 256, 0, stream>>>(offsets, srcs, h1, a1s, a1d, b1, out1);

    // conv2 GEMM + al2 + output linear fused: h3 = (out1@W2)@Wo
    k_gemm23<<<dim3(MT, 1), 256, 0, stream>>>(
        out1, W2t, Wot, h3, a_src2, a_dst2, a2s, a2d);

    // final aggregation writes fp32 out directly
    k_agg2<<<(NN + 7) / 8, 256, 0, stream>>>(offsets, srcs, h3, a2s, a2d, bc, out);
}